// Round 1
// baseline (206.878 us; speedup 1.0000x reference)
//
#include <hip/hip_runtime.h>
#include <hip/hip_bf16.h>
#include <math.h>

typedef __bf16 bf16_t;
typedef __attribute__((ext_vector_type(8))) __bf16 bf16x8;
typedef __attribute__((ext_vector_type(4))) float f32x4;

// ---------------------------------------------------------------------------
// Geometry (fixed by the reference): IN=128, OUT=128, ED=64, NS=32.
// Packed weight layout for MFMA B-operand (16x16x32 bf16):
//   Wp[((kt*8 + nt)*64 + lane)*8 + j] = W[(kt*32 + (lane>>4)*8 + j)*128 + nt*16 + (lane&15)]
// so each lane's 8 B-elements are one contiguous 16B global read.
// ---------------------------------------------------------------------------

__global__ __launch_bounds__(256) void pack_weights_kernel(
    const float* __restrict__ W, const float* __restrict__ W2,
    bf16_t* __restrict__ Wp, bf16_t* __restrict__ W2p) {
  for (int idx = threadIdx.x; idx < 16384; idx += 256) {
    int j  = idx & 7;
    int l  = (idx >> 3) & 63;
    int nt = (idx >> 9) & 7;
    int kt = idx >> 12;
    int k   = kt * 32 + (l >> 4) * 8 + j;
    int col = nt * 16 + (l & 15);
    Wp[idx]  = (bf16_t)W[k * 128 + col];
    W2p[idx] = (bf16_t)W2[k * 128 + col];
  }
}

// ---------------------------------------------------------------------------
// Kernel A: x = input @ W for 32 rows per block; raw f32 written into the
// output buffer columns [0,128) (overwritten with elu(x) by the node kernel).
// ---------------------------------------------------------------------------
__global__ __launch_bounds__(256) void xgemm_kernel(
    const float* __restrict__ input, const bf16_t* __restrict__ Wp,
    float* __restrict__ out, int N) {
  __shared__ __align__(16) bf16_t As[32 * 128];  // swizzled bf16 A tile
  const int t  = threadIdx.x;
  const int rb = blockIdx.x * 32;

  // stage 32x128 f32 -> bf16 LDS (XOR swizzle on 8-elem chunks)
  for (int c = t; c < 512; c += 256) {
    int row = c >> 4;
    int kc  = (c & 15) * 8;
    int grow = rb + row;
    float v[8];
    if (grow < N) {
      const f32x4* p = (const f32x4*)(input + (size_t)grow * 128 + kc);
      f32x4 v0 = p[0], v1 = p[1];
      v[0]=v0[0]; v[1]=v0[1]; v[2]=v0[2]; v[3]=v0[3];
      v[4]=v1[0]; v[5]=v1[1]; v[6]=v1[2]; v[7]=v1[3];
    } else {
      for (int j = 0; j < 8; ++j) v[j] = 0.f;
    }
    bf16x8 b;
    for (int j = 0; j < 8; ++j) b[j] = (bf16_t)v[j];
    *(bf16x8*)(&As[row * 128 + (kc ^ ((row & 7) << 3))]) = b;
  }
  __syncthreads();

  const int w = t >> 6, l = t & 63;
  const int mt = w & 1;
  const int ntg = (w >> 1) * 4;
  const int arow = mt * 16 + (l & 15);

  f32x4 acc[4] = {};
#pragma unroll
  for (int kt = 0; kt < 4; ++kt) {
    bf16x8 af = *(const bf16x8*)(&As[arow * 128 + ((kt * 32 + (l >> 4) * 8) ^ ((arow & 7) << 3))]);
#pragma unroll
    for (int i = 0; i < 4; ++i) {
      bf16x8 bfv = *(const bf16x8*)(&Wp[((kt * 8 + (ntg + i)) * 64 + l) * 8]);
      acc[i] = __builtin_amdgcn_mfma_f32_16x16x32_bf16(af, bfv, acc[i], 0, 0, 0);
    }
  }
#pragma unroll
  for (int i = 0; i < 4; ++i) {
    int col = (ntg + i) * 16 + (l & 15);
#pragma unroll
    for (int j = 0; j < 4; ++j) {
      int row = mt * 16 + (l >> 4) * 4 + j;
      int gr = rb + row;
      if (gr < N) out[(size_t)gr * 320 + col] = acc[i][j];
    }
  }
}

// ---------------------------------------------------------------------------
// Kernel B: fused per-node. neighs = neigh_feat_n @ W2 via MFMA into LDS,
// scores -> leaky(0.8) -> softmax(32) -> h' and e_agg -> elu -> out row (320).
// ---------------------------------------------------------------------------
__global__ __launch_bounds__(256) void node_kernel(
    const float* __restrict__ neigh_feat, const float* __restrict__ edge_emb,
    const float* __restrict__ a, const bf16_t* __restrict__ W2p,
    float* __restrict__ out, int N) {
  const int n = blockIdx.x;
  const int t = threadIdx.x;

  __shared__ __align__(16) bf16_t As[32 * 128];   // 8 KB   bf16 neigh_feat tile
  __shared__ float Ns[32][132];                   // 16.9 KB neighs (padded)
  __shared__ __align__(16) float Es[32 * 64];     // 8 KB   edge tile
  __shared__ float xs[128], axs[128], ans[128], aes[64];
  __shared__ float sraw[32], att[32];
  __shared__ float sxs;

  // ---- P0: loads ----
  {
    const f32x4* ep = (const f32x4*)(edge_emb + (size_t)n * 2048);
    f32x4* esp = (f32x4*)Es;
    esp[t]       = ep[t];
    esp[t + 256] = ep[t + 256];
  }
  if (t < 128) { xs[t] = out[(size_t)n * 320 + t]; axs[t] = a[t]; }
  else         { ans[t - 128] = a[t]; }
  if (t < 64)  aes[t] = a[256 + t];

  const float* nf = neigh_feat + (size_t)n * 32 * 128;
  for (int c = t; c < 512; c += 256) {
    int row = c >> 4;
    int kc  = (c & 15) * 8;
    const f32x4* p = (const f32x4*)(nf + row * 128 + kc);
    f32x4 v0 = p[0], v1 = p[1];
    bf16x8 b;
    b[0]=(bf16_t)v0[0]; b[1]=(bf16_t)v0[1]; b[2]=(bf16_t)v0[2]; b[3]=(bf16_t)v0[3];
    b[4]=(bf16_t)v1[0]; b[5]=(bf16_t)v1[1]; b[6]=(bf16_t)v1[2]; b[7]=(bf16_t)v1[3];
    *(bf16x8*)(&As[row * 128 + (kc ^ ((row & 7) << 3))]) = b;
  }
  __syncthreads();

  // ---- P2: GEMM 32x128 = A(32x128) @ W2(128x128), bf16 MFMA ----
  const int w = t >> 6, l = t & 63;
  const int mt = w & 1;
  const int ntg = (w >> 1) * 4;
  const int arow = mt * 16 + (l & 15);

  f32x4 acc[4] = {};
#pragma unroll
  for (int kt = 0; kt < 4; ++kt) {
    bf16x8 af = *(const bf16x8*)(&As[arow * 128 + ((kt * 32 + (l >> 4) * 8) ^ ((arow & 7) << 3))]);
#pragma unroll
    for (int i = 0; i < 4; ++i) {
      bf16x8 bfv = *(const bf16x8*)(&W2p[((kt * 8 + (ntg + i)) * 64 + l) * 8]);
      acc[i] = __builtin_amdgcn_mfma_f32_16x16x32_bf16(af, bfv, acc[i], 0, 0, 0);
    }
  }
#pragma unroll
  for (int i = 0; i < 4; ++i) {
    int col = (ntg + i) * 16 + (l & 15);
#pragma unroll
    for (int j = 0; j < 4; ++j) {
      int row = mt * 16 + (l >> 4) * 4 + j;
      Ns[row][col] = acc[i][j];
    }
  }
  __syncthreads();

  // ---- P4: scores (without the per-node constant sx) ----
  {
    int s = t >> 3, sub = t & 7;
    float p = 0.f;
    const float* nr = Ns[s];
#pragma unroll
    for (int i = 0; i < 16; ++i) p += nr[sub * 16 + i] * ans[sub * 16 + i];
#pragma unroll
    for (int i = 0; i < 8; ++i)  p += Es[s * 64 + sub * 8 + i] * aes[sub * 8 + i];
    p += __shfl_xor(p, 1);
    p += __shfl_xor(p, 2);
    p += __shfl_xor(p, 4);
    if (sub == 0) sraw[s] = p;
  }
  // sx = dot(x, a_x) by wave 0 (needed: leaky is nonlinear, sx doesn't cancel)
  if (w == 0) {
    float v = xs[l] * axs[l] + xs[l + 64] * axs[l + 64];
    v += __shfl_xor(v, 1);  v += __shfl_xor(v, 2);  v += __shfl_xor(v, 4);
    v += __shfl_xor(v, 8);  v += __shfl_xor(v, 16); v += __shfl_xor(v, 32);
    if (l == 0) sxs = v;
  }
  __syncthreads();

  // ---- softmax over 32 (wave 0; lanes 32..63 mirror lanes 0..31) ----
  if (w == 0) {
    float e = sraw[l & 31] + sxs;
    e = e > 0.f ? e : 0.8f * e;                  // leaky, alpha = 0.8
    float m = e;
    m = fmaxf(m, __shfl_xor(m, 1));
    m = fmaxf(m, __shfl_xor(m, 2));
    m = fmaxf(m, __shfl_xor(m, 4));
    m = fmaxf(m, __shfl_xor(m, 8));
    m = fmaxf(m, __shfl_xor(m, 16));
    float p = expf(e - m);
    float ssum = p;
    ssum += __shfl_xor(ssum, 1);
    ssum += __shfl_xor(ssum, 2);
    ssum += __shfl_xor(ssum, 4);
    ssum += __shfl_xor(ssum, 8);
    ssum += __shfl_xor(ssum, 16);
    if (l < 32) att[l] = p / ssum;
  }
  __syncthreads();

  // ---- P5: aggregation + elu + store ----
  const size_t ob = (size_t)n * 320;
  if (t < 128) {
    float h = 0.f;
#pragma unroll
    for (int s = 0; s < 32; ++s) h += att[s] * Ns[s][t];
    out[ob + 128 + t] = h > 0.f ? h : expm1f(h);
  } else if (t < 192) {
    int c = t - 128;
    float h = 0.f;
#pragma unroll
    for (int s = 0; s < 32; ++s) h += att[s] * Es[s * 64 + c];
    out[ob + 256 + c] = h > 0.f ? h : expm1f(h);
  } else {
    int c = t - 192;
    float v0 = xs[c], v1 = xs[c + 64];
    out[ob + c]      = v0 > 0.f ? v0 : expm1f(v0);
    out[ob + c + 64] = v1 > 0.f ? v1 : expm1f(v1);
  }
}

// ---------------------------------------------------------------------------
extern "C" void kernel_launch(void* const* d_in, const int* in_sizes, int n_in,
                              void* d_out, int out_size, void* d_ws, size_t ws_size,
                              hipStream_t stream) {
  const float* input = (const float*)d_in[0];
  const float* neigh = (const float*)d_in[1];
  const float* edge  = (const float*)d_in[2];
  // d_in[3] = mask (unused by the reference computation)
  const float* W     = (const float*)d_in[4];
  const float* W2    = (const float*)d_in[5];
  const float* a     = (const float*)d_in[6];
  float* out = (float*)d_out;

  const int N = in_sizes[0] / 128;  // 25000

  bf16_t* W2p = (bf16_t*)d_ws;          // 16384 bf16 = 32 KB
  bf16_t* Wp  = W2p + 16384;            // another 32 KB

  pack_weights_kernel<<<1, 256, 0, stream>>>(W, W2, Wp, W2p);
  xgemm_kernel<<<(N + 31) / 32, 256, 0, stream>>>(input, Wp, out, N);
  node_kernel<<<N, 256, 0, stream>>>(neigh, edge, a, W2p, out, N);
}

// Round 2
// 206.337 us; speedup vs baseline: 1.0026x; 1.0026x over previous
//
#include <hip/hip_runtime.h>
#include <hip/hip_bf16.h>
#include <math.h>

typedef __bf16 bf16_t;
typedef __attribute__((ext_vector_type(8))) __bf16 bf16x8;
typedef __attribute__((ext_vector_type(4))) float f32x4;

// ---------------------------------------------------------------------------
// Geometry (fixed): IN=128, OUT=128, ED=64, NS=32.
// Packed weight layout for MFMA B-operand (16x16x32 bf16):
//   Wp[((kt*8 + nt)*64 + lane)*8 + j] = W[(kt*32 + (lane>>4)*8 + j)*128 + nt*16 + (lane&15)]
// ---------------------------------------------------------------------------

__global__ __launch_bounds__(256) void pack_weights_kernel(
    const float* __restrict__ W, const float* __restrict__ W2,
    bf16_t* __restrict__ Wp, bf16_t* __restrict__ W2p) {
  for (int idx = threadIdx.x; idx < 16384; idx += 256) {
    int j  = idx & 7;
    int l  = (idx >> 3) & 63;
    int nt = (idx >> 9) & 7;
    int kt = idx >> 12;
    int k   = kt * 32 + (l >> 4) * 8 + j;
    int col = nt * 16 + (l & 15);
    Wp[idx]  = (bf16_t)W[k * 128 + col];
    W2p[idx] = (bf16_t)W2[k * 128 + col];
  }
}

// ---------------------------------------------------------------------------
// Kernel A: x = input @ W, raw f32 into out cols [0,128) (finalized later).
// ---------------------------------------------------------------------------
__global__ __launch_bounds__(256) void xgemm_kernel(
    const float* __restrict__ input, const bf16_t* __restrict__ Wp,
    float* __restrict__ out, int N) {
  __shared__ __align__(16) bf16_t As[32 * 128];
  const int t  = threadIdx.x;
  const int rb = blockIdx.x * 32;

  for (int c = t; c < 512; c += 256) {
    int row = c >> 4;
    int kc  = (c & 15) * 8;
    int grow = rb + row;
    float v[8];
    if (grow < N) {
      const f32x4* p = (const f32x4*)(input + (size_t)grow * 128 + kc);
      f32x4 v0 = p[0], v1 = p[1];
      v[0]=v0[0]; v[1]=v0[1]; v[2]=v0[2]; v[3]=v0[3];
      v[4]=v1[0]; v[5]=v1[1]; v[6]=v1[2]; v[7]=v1[3];
    } else {
      for (int j = 0; j < 8; ++j) v[j] = 0.f;
    }
    bf16x8 b;
    for (int j = 0; j < 8; ++j) b[j] = (bf16_t)v[j];
    *(bf16x8*)(&As[row * 128 + (kc ^ ((row & 7) << 3))]) = b;
  }
  __syncthreads();

  const int w = t >> 6, l = t & 63;
  const int mt = w & 1;
  const int ntg = (w >> 1) * 4;
  const int arow = mt * 16 + (l & 15);

  f32x4 acc[4] = {};
#pragma unroll
  for (int kt = 0; kt < 4; ++kt) {
    bf16x8 af = *(const bf16x8*)(&As[arow * 128 + ((kt * 32 + (l >> 4) * 8) ^ ((arow & 7) << 3))]);
#pragma unroll
    for (int i = 0; i < 4; ++i) {
      bf16x8 bfv = *(const bf16x8*)(&Wp[((kt * 8 + (ntg + i)) * 64 + l) * 8]);
      acc[i] = __builtin_amdgcn_mfma_f32_16x16x32_bf16(af, bfv, acc[i], 0, 0, 0);
    }
  }
#pragma unroll
  for (int i = 0; i < 4; ++i) {
    int col = (ntg + i) * 16 + (l & 15);
#pragma unroll
    for (int j = 0; j < 4; ++j) {
      int row = mt * 16 + (l >> 4) * 4 + j;
      int gr = rb + row;
      if (gr < N) out[(size_t)gr * 320 + col] = acc[i][j];
    }
  }
}

// ---------------------------------------------------------------------------
// Kernel B: fused per-node. neighs stay in MFMA accumulator registers;
// scores and aggregation computed via shfl reductions + tiny LDS combine.
// LDS ~19 KB -> 6-8 blocks/CU (vs 4 before).
// ---------------------------------------------------------------------------
__global__ __launch_bounds__(256) void node_kernel(
    const float* __restrict__ neigh_feat, const float* __restrict__ edge_emb,
    const float* __restrict__ a, const bf16_t* __restrict__ W2p,
    float* __restrict__ out, int N) {
  const int n = blockIdx.x;
  const int t = threadIdx.x;
  const int w = t >> 6, l = t & 63;

  __shared__ __align__(16) bf16_t As[32 * 128];  // 8 KB  bf16 neigh tile (swizzled)
  __shared__ __align__(16) float Es[32 * 64];    // 8 KB  edge tile
  __shared__ float hws[4][64];                   // 1 KB  h' cross-wave partials
  __shared__ float sp[2][32];                    // score-N cross-wave partials
  __shared__ float se[32];                       // edge score per neighbor
  __shared__ float xs[128];                      // x row
  __shared__ float ans[128];                     // a_n
  __shared__ float att[32];
  __shared__ float sxp[2];

  const size_t ob = (size_t)n * 320;

  // ---- load phase (edge score fused into edge load) ----
  {
    int s = t >> 3, sub = t & 7;
    const f32x4* ep = (const f32x4*)(edge_emb + (size_t)n * 2048 + s * 64 + sub * 8);
    f32x4 e0 = ep[0], e1 = ep[1];
    const f32x4* ap = (const f32x4*)(a + 256 + sub * 8);
    f32x4 a0 = ap[0], a1 = ap[1];
    float p = e0[0]*a0[0] + e0[1]*a0[1] + e0[2]*a0[2] + e0[3]*a0[3]
            + e1[0]*a1[0] + e1[1]*a1[1] + e1[2]*a1[2] + e1[3]*a1[3];
    p += __shfl_xor(p, 1); p += __shfl_xor(p, 2); p += __shfl_xor(p, 4);
    f32x4* esp = (f32x4*)(Es + s * 64 + sub * 8);
    esp[0] = e0; esp[1] = e1;
    if (sub == 0) se[s] = p;
  }
  if (t < 128) {  // waves 0,1: x row + sx partial
    float xv = out[ob + t];
    xs[t] = xv;
    float v = xv * a[t];
    v += __shfl_xor(v, 1);  v += __shfl_xor(v, 2);  v += __shfl_xor(v, 4);
    v += __shfl_xor(v, 8);  v += __shfl_xor(v, 16); v += __shfl_xor(v, 32);
    if (l == 0) sxp[w] = v;
  } else {        // waves 2,3: a_n
    ans[t - 128] = a[t];
  }
  const float* nf = neigh_feat + (size_t)n * 4096;
  for (int c = t; c < 512; c += 256) {
    int row = c >> 4;
    int kc  = (c & 15) * 8;
    const f32x4* p4 = (const f32x4*)(nf + row * 128 + kc);
    f32x4 v0 = p4[0], v1 = p4[1];
    bf16x8 b;
    b[0]=(bf16_t)v0[0]; b[1]=(bf16_t)v0[1]; b[2]=(bf16_t)v0[2]; b[3]=(bf16_t)v0[3];
    b[4]=(bf16_t)v1[0]; b[5]=(bf16_t)v1[1]; b[6]=(bf16_t)v1[2]; b[7]=(bf16_t)v1[3];
    *(bf16x8*)(&As[row * 128 + (kc ^ ((row & 7) << 3))]) = b;
  }
  __syncthreads();

  // ---- MFMA: 32x128 neighs tile, stays in acc[] ----
  const int mt = w & 1;
  const int ntg = (w >> 1) * 4;
  const int arow = mt * 16 + (l & 15);
  f32x4 acc[4] = {};
#pragma unroll
  for (int kt = 0; kt < 4; ++kt) {
    bf16x8 af = *(const bf16x8*)(&As[arow * 128 + ((kt * 32 + (l >> 4) * 8) ^ ((arow & 7) << 3))]);
#pragma unroll
    for (int i = 0; i < 4; ++i) {
      bf16x8 bv = *(const bf16x8*)(&W2p[((kt * 8 + (ntg + i)) * 64 + l) * 8]);
      acc[i] = __builtin_amdgcn_mfma_f32_16x16x32_bf16(af, bv, acc[i], 0, 0, 0);
    }
  }

  // ---- score-N partials straight from the accumulator ----
  // lane holds N[row(j)][col(i)], row(j)=mt*16+(l>>4)*4+j, col(i)=(ntg+i)*16+(l&15)
  float an[4];
#pragma unroll
  for (int i = 0; i < 4; ++i) an[i] = ans[(ntg + i) * 16 + (l & 15)];
#pragma unroll
  for (int j = 0; j < 4; ++j) {
    float p = acc[0][j]*an[0] + acc[1][j]*an[1] + acc[2][j]*an[2] + acc[3][j]*an[3];
    p += __shfl_xor(p, 1); p += __shfl_xor(p, 2);
    p += __shfl_xor(p, 4); p += __shfl_xor(p, 8);
    if ((l & 15) == 0) sp[w >> 1][mt * 16 + (l >> 4) * 4 + j] = p;
  }
  __syncthreads();

  // ---- leaky + softmax over 32 (threads 0..31, all in wave 0) ----
  if (t < 32) {
    float e = sp[0][t] + sp[1][t] + se[t] + sxp[0] + sxp[1];
    e = e > 0.f ? e : 0.8f * e;
    float m = e;
    m = fmaxf(m, __shfl_xor(m, 1));
    m = fmaxf(m, __shfl_xor(m, 2));
    m = fmaxf(m, __shfl_xor(m, 4));
    m = fmaxf(m, __shfl_xor(m, 8));
    m = fmaxf(m, __shfl_xor(m, 16));
    float p = expf(e - m);
    float s2 = p;
    s2 += __shfl_xor(s2, 1);
    s2 += __shfl_xor(s2, 2);
    s2 += __shfl_xor(s2, 4);
    s2 += __shfl_xor(s2, 8);
    s2 += __shfl_xor(s2, 16);
    att[t] = p / s2;
  }
  __syncthreads();

  // ---- h' aggregation from the accumulator ----
  float at[4];
#pragma unroll
  for (int j = 0; j < 4; ++j) at[j] = att[mt * 16 + (l >> 4) * 4 + j];
#pragma unroll
  for (int i = 0; i < 4; ++i) {
    float h = acc[i][0]*at[0] + acc[i][1]*at[1] + acc[i][2]*at[2] + acc[i][3]*at[3];
    h += __shfl_xor(h, 16);
    h += __shfl_xor(h, 32);
    if ((l >> 4) == 0) hws[w][i * 16 + l] = h;  // col = (w>>1)*64 + i*16 + l
  }
  __syncthreads();

  // ---- finalize: elu + store all 320 outputs ----
  if (t < 128) {
    int g = t >> 6, off = t & 63;
    float h = hws[g * 2][off] + hws[g * 2 + 1][off];
    out[ob + 128 + t] = h > 0.f ? h : expm1f(h);
  } else if (t < 192) {
    int c = t - 128;
    float h = 0.f;
#pragma unroll
    for (int s = 0; s < 32; ++s) h += att[s] * Es[s * 64 + c];
    out[ob + 256 + c] = h > 0.f ? h : expm1f(h);
  } else {
    int c = t - 192;
    float v0 = xs[c], v1 = xs[c + 64];
    out[ob + c]      = v0 > 0.f ? v0 : expm1f(v0);
    out[ob + c + 64] = v1 > 0.f ? v1 : expm1f(v1);
  }
}

// ---------------------------------------------------------------------------
extern "C" void kernel_launch(void* const* d_in, const int* in_sizes, int n_in,
                              void* d_out, int out_size, void* d_ws, size_t ws_size,
                              hipStream_t stream) {
  const float* input = (const float*)d_in[0];
  const float* neigh = (const float*)d_in[1];
  const float* edge  = (const float*)d_in[2];
  // d_in[3] = mask (unused by the reference computation)
  const float* W     = (const float*)d_in[4];
  const float* W2    = (const float*)d_in[5];
  const float* a     = (const float*)d_in[6];
  float* out = (float*)d_out;

  const int N = in_sizes[0] / 128;  // 25000

  bf16_t* W2p = (bf16_t*)d_ws;          // 32 KB
  bf16_t* Wp  = W2p + 16384;            // 32 KB

  pack_weights_kernel<<<1, 256, 0, stream>>>(W, W2, Wp, W2p);
  xgemm_kernel<<<(N + 31) / 32, 256, 0, stream>>>(input, Wp, out, N);
  node_kernel<<<N, 256, 0, stream>>>(neigh, edge, a, W2p, out, N);
}

// Round 3
// 204.829 us; speedup vs baseline: 1.0100x; 1.0074x over previous
//
#include <hip/hip_runtime.h>
#include <hip/hip_bf16.h>
#include <math.h>

typedef __bf16 bf16_t;
typedef __attribute__((ext_vector_type(8))) __bf16 bf16x8;
typedef __attribute__((ext_vector_type(4))) float f32x4;

#define NB 8  // nodes per block in the pipelined node kernel

// ---------------------------------------------------------------------------
// Packed weight layout for MFMA B-operand (16x16x32 bf16):
//   Wp[((kt*8 + nt)*64 + lane)*8 + j] = W[(kt*32 + (lane>>4)*8 + j)*128 + nt*16 + (lane&15)]
// ---------------------------------------------------------------------------
__global__ __launch_bounds__(256) void pack_weights_kernel(
    const float* __restrict__ W, const float* __restrict__ W2,
    bf16_t* __restrict__ Wp, bf16_t* __restrict__ W2p) {
  int idx = blockIdx.x * 256 + threadIdx.x;   // grid = 64 blocks
  int j  = idx & 7;
  int l  = (idx >> 3) & 63;
  int nt = (idx >> 9) & 7;
  int kt = idx >> 12;
  int k   = kt * 32 + (l >> 4) * 8 + j;
  int col = nt * 16 + (l & 15);
  Wp[idx]  = (bf16_t)W[k * 128 + col];
  W2p[idx] = (bf16_t)W2[k * 128 + col];
}

// ---------------------------------------------------------------------------
// Kernel A: x = input @ W. Writes elu(x) to out cols [0,128) and
// sx[n] = dot(x_n, a_x) to sxv[] (raw, pre-elu).
// ---------------------------------------------------------------------------
__global__ __launch_bounds__(256) void xgemm_kernel(
    const float* __restrict__ input, const bf16_t* __restrict__ Wp,
    const float* __restrict__ a,
    float* __restrict__ out, float* __restrict__ sxv, int N) {
  __shared__ __align__(16) bf16_t As[32 * 128];
  __shared__ float sp2[2][32];
  const int t  = threadIdx.x;
  const int rb = blockIdx.x * 32;
  const int w = t >> 6, l = t & 63;

  for (int c = t; c < 512; c += 256) {
    int row = c >> 4;
    int kc  = (c & 15) * 8;
    int grow = rb + row;
    float v[8];
    if (grow < N) {
      const f32x4* p = (const f32x4*)(input + (size_t)grow * 128 + kc);
      f32x4 v0 = p[0], v1 = p[1];
      v[0]=v0[0]; v[1]=v0[1]; v[2]=v0[2]; v[3]=v0[3];
      v[4]=v1[0]; v[5]=v1[1]; v[6]=v1[2]; v[7]=v1[3];
    } else {
      for (int j = 0; j < 8; ++j) v[j] = 0.f;
    }
    bf16x8 b;
    for (int j = 0; j < 8; ++j) b[j] = (bf16_t)v[j];
    *(bf16x8*)(&As[row * 128 + (kc ^ ((row & 7) << 3))]) = b;
  }
  __syncthreads();

  const int mt = w & 1;
  const int ntg = (w >> 1) * 4;
  const int arow = mt * 16 + (l & 15);

  float ax[4];
#pragma unroll
  for (int i = 0; i < 4; ++i) ax[i] = a[(ntg + i) * 16 + (l & 15)];

  f32x4 acc[4] = {};
#pragma unroll
  for (int kt = 0; kt < 4; ++kt) {
    bf16x8 af = *(const bf16x8*)(&As[arow * 128 + ((kt * 32 + (l >> 4) * 8) ^ ((arow & 7) << 3))]);
#pragma unroll
    for (int i = 0; i < 4; ++i) {
      bf16x8 bfv = *(const bf16x8*)(&Wp[((kt * 8 + (ntg + i)) * 64 + l) * 8]);
      acc[i] = __builtin_amdgcn_mfma_f32_16x16x32_bf16(af, bfv, acc[i], 0, 0, 0);
    }
  }

  // sx partials: row = mt*16+(l>>4)*4+j
#pragma unroll
  for (int j = 0; j < 4; ++j) {
    float p = acc[0][j]*ax[0] + acc[1][j]*ax[1] + acc[2][j]*ax[2] + acc[3][j]*ax[3];
    p += __shfl_xor(p, 1); p += __shfl_xor(p, 2);
    p += __shfl_xor(p, 4); p += __shfl_xor(p, 8);
    if ((l & 15) == 0) sp2[w >> 1][mt * 16 + (l >> 4) * 4 + j] = (w & 2) ? p : p;  // cg = w>>1
  }
  // NOTE: waves 0,1 are cg0 (cols 0..63), waves 2,3 cg1. Rows are disjoint per mt.
  __syncthreads();
  if (t < 32) {
    int gr = rb + t;
    if (gr < N) sxv[gr] = sp2[0][t] + sp2[1][t];
  }

#pragma unroll
  for (int i = 0; i < 4; ++i) {
    int col = (ntg + i) * 16 + (l & 15);
#pragma unroll
    for (int j = 0; j < 4; ++j) {
      int row = mt * 16 + (l >> 4) * 4 + j;
      int gr = rb + row;
      if (gr < N) {
        float v = acc[i][j];
        out[(size_t)gr * 320 + col] = v > 0.f ? v : __expf(v) - 1.f;
      }
    }
  }
}

// ---------------------------------------------------------------------------
// Kernel B: pipelined per-node fusion, NB nodes per block.
// Loads for node k+1 are issued during node k's compute (reg-staged, T14).
// ---------------------------------------------------------------------------
__global__ __launch_bounds__(256) void node_kernel(
    const float* __restrict__ neigh_feat, const float* __restrict__ edge_emb,
    const float* __restrict__ a, const bf16_t* __restrict__ W2p,
    const float* __restrict__ sxv, float* __restrict__ out) {
  const int t = threadIdx.x;
  const int w = t >> 6, l = t & 63;
  const int n0 = blockIdx.x * NB;

  __shared__ __align__(16) bf16_t As[2][32 * 128];  // 16 KB dbuf neigh (swizzled)
  __shared__ __align__(16) bf16_t Eb[2][32 * 64];   // 8 KB  dbuf edge (row-major)
  __shared__ float hws[4][64];
  __shared__ float sp[2][32];
  __shared__ float se[32];
  __shared__ float att[32];

  const int mt = w & 1;
  const int ntg = (w >> 1) * 4;
  const int arow = mt * 16 + (l & 15);
  const int es = t >> 3, sub = t & 7;   // edge: neighbor es, cols sub*8..+8
  const int r0 = t >> 4, kc0 = (t & 15) * 8;  // neigh chunks: rows r0 and r0+16
  const int swz = (r0 & 7) << 3;

  // per-block constants in registers
  const f32x4 ae0 = *(const f32x4*)(a + 256 + sub * 8);
  const f32x4 ae1 = *(const f32x4*)(a + 256 + sub * 8 + 4);
  float an[4];
#pragma unroll
  for (int i = 0; i < 4; ++i) an[i] = a[128 + (ntg + i) * 16 + (l & 15)];

  f32x4 nv0, nv1, nv2, nv3, ev0, ev1;
#define ISSUE(node_) do {                                                  \
    const float* nf_ = neigh_feat + (size_t)(node_) * 4096;                \
    nv0 = *(const f32x4*)(nf_ + r0 * 128 + kc0);                           \
    nv1 = *(const f32x4*)(nf_ + r0 * 128 + kc0 + 4);                       \
    nv2 = *(const f32x4*)(nf_ + (r0 + 16) * 128 + kc0);                    \
    nv3 = *(const f32x4*)(nf_ + (r0 + 16) * 128 + kc0 + 4);                \
    const float* ee_ = edge_emb + (size_t)(node_) * 2048 + es * 64 + sub * 8; \
    ev0 = *(const f32x4*)(ee_);                                            \
    ev1 = *(const f32x4*)(ee_ + 4);                                        \
  } while (0)

  ISSUE(n0);
  int buf = 0;

#pragma unroll 1
  for (int k = 0; k < NB; ++k) {
    const int node = n0 + k;

    // ---- write phase: cvt staged regs -> LDS; edge score from regs ----
    {
      float p = ev0[0]*ae0[0] + ev0[1]*ae0[1] + ev0[2]*ae0[2] + ev0[3]*ae0[3]
              + ev1[0]*ae1[0] + ev1[1]*ae1[1] + ev1[2]*ae1[2] + ev1[3]*ae1[3];
      p += __shfl_xor(p, 1); p += __shfl_xor(p, 2); p += __shfl_xor(p, 4);
      if (sub == 0) se[es] = p;
      bf16x8 b0, b1, eb;
#pragma unroll
      for (int j = 0; j < 4; ++j) {
        b0[j] = (bf16_t)nv0[j]; b0[j+4] = (bf16_t)nv1[j];
        b1[j] = (bf16_t)nv2[j]; b1[j+4] = (bf16_t)nv3[j];
        eb[j] = (bf16_t)ev0[j]; eb[j+4] = (bf16_t)ev1[j];
      }
      *(bf16x8*)(&As[buf][r0 * 128 + (kc0 ^ swz)])        = b0;
      *(bf16x8*)(&As[buf][(r0 + 16) * 128 + (kc0 ^ swz)]) = b1;
      *(bf16x8*)(&Eb[buf][es * 64 + sub * 8])             = eb;
    }
    __syncthreads();

    // issue next node's loads; they fly under this node's compute
    if (k + 1 < NB) ISSUE(node + 1);

    // ---- MFMA: neighs tile in acc ----
    f32x4 acc[4] = {};
#pragma unroll
    for (int kt = 0; kt < 4; ++kt) {
      bf16x8 af = *(const bf16x8*)(&As[buf][arow * 128 + ((kt * 32 + (l >> 4) * 8) ^ ((arow & 7) << 3))]);
#pragma unroll
      for (int i = 0; i < 4; ++i) {
        bf16x8 bv = *(const bf16x8*)(&W2p[((kt * 8 + (ntg + i)) * 64 + l) * 8]);
        acc[i] = __builtin_amdgcn_mfma_f32_16x16x32_bf16(af, bv, acc[i], 0, 0, 0);
      }
    }

    // ---- score-N partials from the accumulator ----
#pragma unroll
    for (int j = 0; j < 4; ++j) {
      float p = acc[0][j]*an[0] + acc[1][j]*an[1] + acc[2][j]*an[2] + acc[3][j]*an[3];
      p += __shfl_xor(p, 1); p += __shfl_xor(p, 2);
      p += __shfl_xor(p, 4); p += __shfl_xor(p, 8);
      if ((l & 15) == 0) sp[w >> 1][mt * 16 + (l >> 4) * 4 + j] = p;
    }
    __syncthreads();

    // ---- softmax (redundant in all waves; saves a barrier) ----
    float at[4];
    {
      const float sx = sxv[node];
      int s = l & 31;
      float e = sp[0][s] + sp[1][s] + se[s] + sx;
      e = e > 0.f ? e : 0.8f * e;
      float m = e;
      m = fmaxf(m, __shfl_xor(m, 1));
      m = fmaxf(m, __shfl_xor(m, 2));
      m = fmaxf(m, __shfl_xor(m, 4));
      m = fmaxf(m, __shfl_xor(m, 8));
      m = fmaxf(m, __shfl_xor(m, 16));
      float pe = __expf(e - m);
      float s2 = pe;
      s2 += __shfl_xor(s2, 1);
      s2 += __shfl_xor(s2, 2);
      s2 += __shfl_xor(s2, 4);
      s2 += __shfl_xor(s2, 8);
      s2 += __shfl_xor(s2, 16);
      float av = pe / s2;
      if (t < 32) att[t] = av;
#pragma unroll
      for (int j = 0; j < 4; ++j) at[j] = __shfl(av, mt * 16 + (l >> 4) * 4 + j);
    }

    // ---- h' partials from the accumulator ----
#pragma unroll
    for (int i = 0; i < 4; ++i) {
      float h = acc[i][0]*at[0] + acc[i][1]*at[1] + acc[i][2]*at[2] + acc[i][3]*at[3];
      h += __shfl_xor(h, 16);
      h += __shfl_xor(h, 32);
      if ((l >> 4) == 0) hws[w][i * 16 + l] = h;
    }
    __syncthreads();

    // ---- stores: h' (t<128), e_agg (t 128..191) ----
    {
      const size_t ob = (size_t)node * 320;
      if (t < 128) {
        int g = t >> 6, off = t & 63;
        float h = hws[g * 2][off] + hws[g * 2 + 1][off];
        out[ob + 128 + t] = h > 0.f ? h : __expf(h) - 1.f;
      } else if (t < 192) {
        int c = t - 128;
        float hsum = 0.f;
#pragma unroll
        for (int s = 0; s < 32; ++s) hsum += att[s] * (float)Eb[buf][s * 64 + c];
        out[ob + 256 + c] = hsum > 0.f ? hsum : __expf(hsum) - 1.f;
      }
    }
    // no barrier needed here: next phase's LDS writes (se, As/Eb[buf^1]) don't
    // alias this phase's reads (hws, att, Eb[buf]), and sp/att/hws rewrites
    // are separated by the next iteration's barriers.
    buf ^= 1;
  }
#undef ISSUE
}

// ---------------------------------------------------------------------------
extern "C" void kernel_launch(void* const* d_in, const int* in_sizes, int n_in,
                              void* d_out, int out_size, void* d_ws, size_t ws_size,
                              hipStream_t stream) {
  const float* input = (const float*)d_in[0];
  const float* neigh = (const float*)d_in[1];
  const float* edge  = (const float*)d_in[2];
  // d_in[3] = mask (unused by the reference computation)
  const float* W     = (const float*)d_in[4];
  const float* W2    = (const float*)d_in[5];
  const float* a     = (const float*)d_in[6];
  float* out = (float*)d_out;

  const int N = in_sizes[0] / 128;  // 25000

  bf16_t* W2p = (bf16_t*)d_ws;                         // 32 KB
  bf16_t* Wp  = W2p + 16384;                           // 32 KB
  float*  sxv = (float*)((char*)d_ws + 65536);         // N floats

  pack_weights_kernel<<<64, 256, 0, stream>>>(W, W2, Wp, W2p);
  xgemm_kernel<<<(N + 31) / 32, 256, 0, stream>>>(input, Wp, a, out, sxv, N);
  node_kernel<<<N / NB, 256, 0, stream>>>(neigh, edge, a, W2p, sxv, out);
}

// Round 4
// 164.421 us; speedup vs baseline: 1.2582x; 1.2458x over previous
//
#include <hip/hip_runtime.h>
#include <hip/hip_bf16.h>
#include <math.h>

typedef __bf16 bf16_t;
typedef __attribute__((ext_vector_type(8))) __bf16 bf16x8;
typedef __attribute__((ext_vector_type(4))) float f32x4;
typedef __attribute__((ext_vector_type(2))) float f32x2;

#define NB 8  // nodes per block in the streaming kernel

// ---------------------------------------------------------------------------
// pack: Wp/W2p in MFMA B-fragment layout + w2an = W2 @ a_n (f32).
//   Wp[((kt*8+nt)*64+lane)*8+j] = W[(kt*32+(lane>>4)*8+j)*128 + nt*16+(lane&15)]
// ---------------------------------------------------------------------------
__global__ __launch_bounds__(256) void pack_weights_kernel(
    const float* __restrict__ W, const float* __restrict__ W2,
    const float* __restrict__ a,
    bf16_t* __restrict__ Wp, bf16_t* __restrict__ W2p,
    float* __restrict__ w2an) {
  int idx = blockIdx.x * 256 + threadIdx.x;   // grid = 64 blocks
  int j  = idx & 7;
  int l  = (idx >> 3) & 63;
  int nt = (idx >> 9) & 7;
  int kt = idx >> 12;
  int k   = kt * 32 + (l >> 4) * 8 + j;
  int col = nt * 16 + (l & 15);
  Wp[idx]  = (bf16_t)W[k * 128 + col];
  W2p[idx] = (bf16_t)W2[k * 128 + col];
  if (blockIdx.x == 0 && threadIdx.x < 128) {
    const float* r = W2 + threadIdx.x * 128;
    float s = 0.f;
    for (int c = 0; c < 128; ++c) s += r[c] * a[128 + c];
    w2an[threadIdx.x] = s;   // w2an[k] = dot(W2 row k, a_n)
  }
}

// ---------------------------------------------------------------------------
// gemm: dst_cols[col_off..col_off+128) = elu(src(N x 128) @ Wpk).
// If sxv != null also writes sx[n] = dot(row_n, a[0:128]-projected) via acc.
// Used for x = input@W (col_off=0, sxv) and h' = agg@W2 (col_off=128).
// ---------------------------------------------------------------------------
__global__ __launch_bounds__(256) void gemm_kernel(
    const float* __restrict__ src, const bf16_t* __restrict__ Wpk,
    const float* __restrict__ a,
    float* __restrict__ out, float* __restrict__ sxv, int col_off, int N) {
  __shared__ __align__(16) bf16_t As[32 * 128];
  __shared__ float sp2[2][32];
  const int t  = threadIdx.x;
  const int rb = blockIdx.x * 32;
  const int w = t >> 6, l = t & 63;

  for (int c = t; c < 512; c += 256) {
    int row = c >> 4;
    int kc  = (c & 15) * 8;
    int grow = rb + row;
    float v[8];
    if (grow < N) {
      const f32x4* p = (const f32x4*)(src + (size_t)grow * 128 + kc);
      f32x4 v0 = p[0], v1 = p[1];
      v[0]=v0[0]; v[1]=v0[1]; v[2]=v0[2]; v[3]=v0[3];
      v[4]=v1[0]; v[5]=v1[1]; v[6]=v1[2]; v[7]=v1[3];
    } else {
      for (int j = 0; j < 8; ++j) v[j] = 0.f;
    }
    bf16x8 b;
    for (int j = 0; j < 8; ++j) b[j] = (bf16_t)v[j];
    *(bf16x8*)(&As[row * 128 + (kc ^ ((row & 7) << 3))]) = b;
  }
  __syncthreads();

  const int mt = w & 1;
  const int ntg = (w >> 1) * 4;
  const int arow = mt * 16 + (l & 15);

  f32x4 acc[4] = {};
#pragma unroll
  for (int kt = 0; kt < 4; ++kt) {
    bf16x8 af = *(const bf16x8*)(&As[arow * 128 + ((kt * 32 + (l >> 4) * 8) ^ ((arow & 7) << 3))]);
#pragma unroll
    for (int i = 0; i < 4; ++i) {
      bf16x8 bfv = *(const bf16x8*)(&Wpk[((kt * 8 + (ntg + i)) * 64 + l) * 8]);
      acc[i] = __builtin_amdgcn_mfma_f32_16x16x32_bf16(af, bfv, acc[i], 0, 0, 0);
    }
  }

  if (sxv) {  // sx partials: row = mt*16+(l>>4)*4+j
    float ax[4];
#pragma unroll
    for (int i = 0; i < 4; ++i) ax[i] = a[(ntg + i) * 16 + (l & 15)];
#pragma unroll
    for (int j = 0; j < 4; ++j) {
      float p = acc[0][j]*ax[0] + acc[1][j]*ax[1] + acc[2][j]*ax[2] + acc[3][j]*ax[3];
      p += __shfl_xor(p, 1); p += __shfl_xor(p, 2);
      p += __shfl_xor(p, 4); p += __shfl_xor(p, 8);
      if ((l & 15) == 0) sp2[w >> 1][mt * 16 + (l >> 4) * 4 + j] = p;
    }
    __syncthreads();
    if (t < 32) {
      int gr = rb + t;
      if (gr < N) sxv[gr] = sp2[0][t] + sp2[1][t];
    }
  }

#pragma unroll
  for (int i = 0; i < 4; ++i) {
    int col = (ntg + i) * 16 + (l & 15);
#pragma unroll
    for (int j = 0; j < 4; ++j) {
      int row = mt * 16 + (l >> 4) * 4 + j;
      int gr = rb + row;
      if (gr < N) {
        float v = acc[i][j];
        out[(size_t)gr * 320 + col_off + col] = v > 0.f ? v : __expf(v) - 1.f;
      }
    }
  }
}

// ---------------------------------------------------------------------------
// Streaming node kernel (NO GEMM): per node, scores from raw data vs w2an/a_e,
// softmax(32), then att-weighted column sums:
//   agg_nf[c] = sum_s att[s]*nf[s][c]  -> aggbuf   (h' = aggbuf @ W2 later)
//   e_agg[c]  = sum_s att[s]*E[s][c]   -> elu -> out[256:320]
// ---------------------------------------------------------------------------
__global__ __launch_bounds__(256) void node_kernel(
    const float* __restrict__ neigh_feat, const float* __restrict__ edge_emb,
    const float* __restrict__ a, const float* __restrict__ w2an,
    const float* __restrict__ sxv, float* __restrict__ aggbuf,
    float* __restrict__ out) {
  const int t = threadIdx.x;
  const int w = t >> 6, l = t & 63;
  const int n0 = blockIdx.x * NB;

  __shared__ __align__(16) bf16_t As[2][32 * 128];  // 16 KB dbuf neigh (swizzled)
  __shared__ __align__(16) bf16_t Eb[2][32 * 64];   // 8 KB  dbuf edge (swizzled)
  __shared__ float srow[2][32];                     // neigh-score per row
  __shared__ float se[2][32];                       // edge-score per row

  const int es = t >> 3, sub = t & 7;          // edge: row es, cols sub*8..+8
  const int r0 = t >> 4, kc0 = (t & 15) * 8;   // neigh: rows r0,r0+16, cols kc0..+8
  const int swz = (r0 & 7) << 3;

  // loop-invariant vectors in registers (L2-cached loads, once per block)
  const f32x4 ae0 = *(const f32x4*)(a + 256 + sub * 8);
  const f32x4 ae1 = *(const f32x4*)(a + 256 + sub * 8 + 4);
  const f32x4 wn0 = *(const f32x4*)(w2an + kc0);
  const f32x4 wn1 = *(const f32x4*)(w2an + kc0 + 4);

  f32x4 nv0, nv1, nv2, nv3, ev0, ev1;
#define ISSUE(node_) do {                                                   \
    const float* nf_ = neigh_feat + (size_t)(node_) * 4096;                 \
    nv0 = *(const f32x4*)(nf_ + r0 * 128 + kc0);                            \
    nv1 = *(const f32x4*)(nf_ + r0 * 128 + kc0 + 4);                        \
    nv2 = *(const f32x4*)(nf_ + (r0 + 16) * 128 + kc0);                     \
    nv3 = *(const f32x4*)(nf_ + (r0 + 16) * 128 + kc0 + 4);                 \
    const float* ee_ = edge_emb + (size_t)(node_) * 2048 + es * 64 + sub * 8; \
    ev0 = *(const f32x4*)(ee_);                                             \
    ev1 = *(const f32x4*)(ee_ + 4);                                         \
  } while (0)

  ISSUE(n0);
  int buf = 0;

#pragma unroll 1
  for (int k = 0; k < NB; ++k) {
    const int node = n0 + k;

    // ---- write phase: score partials from regs, cvt -> LDS ----
    {
      float pe = ev0[0]*ae0[0] + ev0[1]*ae0[1] + ev0[2]*ae0[2] + ev0[3]*ae0[3]
               + ev1[0]*ae1[0] + ev1[1]*ae1[1] + ev1[2]*ae1[2] + ev1[3]*ae1[3];
      pe += __shfl_xor(pe, 1); pe += __shfl_xor(pe, 2); pe += __shfl_xor(pe, 4);
      if (sub == 0) se[buf][es] = pe;

      float p0 = nv0[0]*wn0[0] + nv0[1]*wn0[1] + nv0[2]*wn0[2] + nv0[3]*wn0[3]
               + nv1[0]*wn1[0] + nv1[1]*wn1[1] + nv1[2]*wn1[2] + nv1[3]*wn1[3];
      float p1 = nv2[0]*wn0[0] + nv2[1]*wn0[1] + nv2[2]*wn0[2] + nv2[3]*wn0[3]
               + nv3[0]*wn1[0] + nv3[1]*wn1[1] + nv3[2]*wn1[2] + nv3[3]*wn1[3];
      p0 += __shfl_xor(p0, 1); p0 += __shfl_xor(p0, 2);
      p0 += __shfl_xor(p0, 4); p0 += __shfl_xor(p0, 8);
      p1 += __shfl_xor(p1, 1); p1 += __shfl_xor(p1, 2);
      p1 += __shfl_xor(p1, 4); p1 += __shfl_xor(p1, 8);
      if ((l & 15) == 0) { srow[buf][r0] = p0; srow[buf][r0 + 16] = p1; }

      bf16x8 b0, b1, ebv;
#pragma unroll
      for (int j = 0; j < 4; ++j) {
        b0[j] = (bf16_t)nv0[j]; b0[j+4] = (bf16_t)nv1[j];
        b1[j] = (bf16_t)nv2[j]; b1[j+4] = (bf16_t)nv3[j];
        ebv[j] = (bf16_t)ev0[j]; ebv[j+4] = (bf16_t)ev1[j];
      }
      *(bf16x8*)(&As[buf][r0 * 128 + (kc0 ^ swz)])        = b0;
      *(bf16x8*)(&As[buf][(r0 + 16) * 128 + (kc0 ^ swz)]) = b1;
      *(bf16x8*)(&Eb[buf][es * 64 + ((sub ^ (es & 7)) * 8)]) = ebv;
    }
    __syncthreads();

    if (k + 1 < NB) ISSUE(node + 1);  // next node's loads fly under compute

    // ---- leaky + softmax over 32 (redundant per wave; av = att[l&31]) ----
    float av;
    {
      const float sx = sxv[node];
      int s = l & 31;
      float e = srow[buf][s] + se[buf][s] + sx;
      e = e > 0.f ? e : 0.8f * e;
      float m = e;
      m = fmaxf(m, __shfl_xor(m, 1));
      m = fmaxf(m, __shfl_xor(m, 2));
      m = fmaxf(m, __shfl_xor(m, 4));
      m = fmaxf(m, __shfl_xor(m, 8));
      m = fmaxf(m, __shfl_xor(m, 16));
      float pe2 = __expf(e - m);
      float s2 = pe2;
      s2 += __shfl_xor(s2, 1);
      s2 += __shfl_xor(s2, 2);
      s2 += __shfl_xor(s2, 4);
      s2 += __shfl_xor(s2, 8);
      s2 += __shfl_xor(s2, 16);
      av = pe2 / s2;
    }

    // ---- aggregation: column-pair ownership, bf16 LDS bounce ----
    if (w == 0) {           // agg_nf: wave 0, lane owns cols (2l, 2l+1)
      const int g = l >> 2;          // 16B-granule of col pair (0..15)
      const int boff = (l & 3) * 4;  // byte offset within granule
      const char* base = (const char*)As[buf];
      float a0 = 0.f, a1 = 0.f;
#pragma unroll
      for (int s = 0; s < 32; ++s) {
        unsigned u = *(const unsigned*)(base + s * 256 + ((g ^ (s & 7)) * 16) + boff);
        float as = __shfl(av, s);
        a0 = fmaf(as, __uint_as_float(u << 16), a0);
        a1 = fmaf(as, __uint_as_float(u & 0xffff0000u), a1);
      }
      f32x2 st = {a0, a1};
      *(f32x2*)(aggbuf + (size_t)node * 128 + 2 * l) = st;
    } else if (w == 1 && l < 32) {   // e_agg: lane owns cols (2l, 2l+1)
      const int g = l >> 2;          // 0..7
      const int boff = (l & 3) * 4;
      const char* base = (const char*)Eb[buf];
      float a0 = 0.f, a1 = 0.f;
#pragma unroll
      for (int s = 0; s < 32; ++s) {
        unsigned u = *(const unsigned*)(base + s * 128 + ((g ^ (s & 7)) * 16) + boff);
        float as = __shfl(av, s);
        a0 = fmaf(as, __uint_as_float(u << 16), a0);
        a1 = fmaf(as, __uint_as_float(u & 0xffff0000u), a1);
      }
      a0 = a0 > 0.f ? a0 : __expf(a0) - 1.f;
      a1 = a1 > 0.f ? a1 : __expf(a1) - 1.f;
      f32x2 st = {a0, a1};
      *(f32x2*)(out + (size_t)node * 320 + 256 + 2 * l) = st;
    }
    // dbuf: next iteration writes As/Eb[buf^1], srow/se[buf^1] -> no barrier
    buf ^= 1;
  }
#undef ISSUE
}

// ---------------------------------------------------------------------------
extern "C" void kernel_launch(void* const* d_in, const int* in_sizes, int n_in,
                              void* d_out, int out_size, void* d_ws, size_t ws_size,
                              hipStream_t stream) {
  const float* input = (const float*)d_in[0];
  const float* neigh = (const float*)d_in[1];
  const float* edge  = (const float*)d_in[2];
  // d_in[3] = mask (unused by the reference computation)
  const float* W     = (const float*)d_in[4];
  const float* W2    = (const float*)d_in[5];
  const float* a     = (const float*)d_in[6];
  float* out = (float*)d_out;

  const int N = in_sizes[0] / 128;  // 25000

  bf16_t* W2p  = (bf16_t*)d_ws;                          // 32 KB
  bf16_t* Wp   = W2p + 16384;                            // 32 KB
  float*  w2an = (float*)((char*)d_ws + 65536);          // 512 B
  float*  sxv  = (float*)((char*)d_ws + 66560);          // N f32
  float*  agg  = (float*)((char*)d_ws + 262144);         // N*128 f32 (12.8 MB)

  pack_weights_kernel<<<64, 256, 0, stream>>>(W, W2, a, Wp, W2p, w2an);
  gemm_kernel<<<(N + 31) / 32, 256, 0, stream>>>(input, Wp, a, out, sxv, 0, N);
  node_kernel<<<N / NB, 256, 0, stream>>>(neigh, edge, a, w2an, sxv, agg, out);
  gemm_kernel<<<(N + 31) / 32, 256, 0, stream>>>(agg, W2p, a, out, nullptr, 128, N);
}